// Round 7
// baseline (495.484 us; speedup 1.0000x reference)
//
#include <hip/hip_runtime.h>
#include <hip/hip_bf16.h>
#include <stdint.h>

#define D_MODEL 1024
#define S_LEN 1024
#define BATCH 2
#define NHEADS 16
#define DK 64
#define DFF 4096

typedef __attribute__((ext_vector_type(8))) short short8;
typedef __attribute__((ext_vector_type(4))) float f32x4;

__device__ __forceinline__ unsigned short f2bf(float f) {
  union { float f; unsigned u; } v; v.f = f;
  unsigned r = v.u + 0x7FFFu + ((v.u >> 16) & 1u);
  return (unsigned short)(r >> 16);
}

__device__ __forceinline__ float bf2f(unsigned short s) {
  union { float f; unsigned u; } v; v.u = ((unsigned)s) << 16;
  return v.f;
}

__device__ __forceinline__ void gll16(const void* g, void* l) {
  __builtin_amdgcn_global_load_lds(
      (const __attribute__((address_space(1))) void*)g,
      (__attribute__((address_space(3))) void*)l, 16, 0, 0);
}

// ---------------- LayerNorm: f32 in -> bf16 out (ddof=1 std per reference) ----
__global__ __launch_bounds__(256)
void ln_kernel(const float* __restrict__ x,
               const float* __restrict__ alpha,
               const float* __restrict__ beta,
               unsigned short* __restrict__ out) {
  const int row = blockIdx.x;
  const int tid = threadIdx.x;
  const float4 v = ((const float4*)(x + (int64_t)row * D_MODEL))[tid];
  float s = v.x + v.y + v.z + v.w;
  float ss = v.x * v.x + v.y * v.y + v.z * v.z + v.w * v.w;
  #pragma unroll
  for (int m = 32; m; m >>= 1) {
    s += __shfl_down(s, m);
    ss += __shfl_down(ss, m);
  }
  __shared__ float red[10];
  const int wave = tid >> 6;
  if ((tid & 63) == 0) { red[wave] = s; red[4 + wave] = ss; }
  __syncthreads();
  if (tid == 0) {
    float S = red[0] + red[1] + red[2] + red[3];
    float SS = red[4] + red[5] + red[6] + red[7];
    float mean = S * (1.f / 1024.f);
    float var = (SS - 1024.f * mean * mean) * (1.f / 1023.f);
    float inv = 1.f / (sqrtf(fmaxf(var, 0.f)) + 1e-6f);
    red[8] = mean; red[9] = inv;
  }
  __syncthreads();
  const float mean = red[8], inv = red[9];
  const float4 a = ((const float4*)alpha)[tid];
  const float4 bb = ((const float4*)beta)[tid];
  union { unsigned short us[4]; uint2 u2; } pk;
  pk.us[0] = f2bf(a.x * (v.x - mean) * inv + bb.x);
  pk.us[1] = f2bf(a.y * (v.y - mean) * inv + bb.y);
  pk.us[2] = f2bf(a.z * (v.z - mean) * inv + bb.z);
  pk.us[3] = f2bf(a.w * (v.w - mean) * inv + bb.w);
  ((uint2*)(out + (int64_t)row * D_MODEL))[tid] = pk.u2;
}

// ---------------- All four weight transposes in ONE launch -------------------
__global__ __launch_bounds__(256)
void wtall_kernel(const float* __restrict__ Wq, const float* __restrict__ Wo,
                  const float* __restrict__ W1, const float* __restrict__ W2,
                  unsigned short* __restrict__ WqT, unsigned short* __restrict__ WoT,
                  unsigned short* __restrict__ W1T, unsigned short* __restrict__ W2T) {
  __shared__ unsigned short tile[32][33];
  int id = blockIdx.x;
  const float* W; unsigned short* Wt; int K, N, bx, by;
  if (id < 1024)      { W = Wq; Wt = WqT; K = 1024; N = 1024; bx = id & 31;  by = id >> 5; }
  else if (id < 2048) { id -= 1024; W = Wo; Wt = WoT; K = 1024; N = 1024; bx = id & 31;  by = id >> 5; }
  else if (id < 6144) { id -= 2048; W = W1; Wt = W1T; K = 1024; N = 4096; bx = id & 127; by = id >> 7; }
  else                { id -= 6144; W = W2; Wt = W2T; K = 4096; N = 1024; bx = id & 31;  by = id >> 5; }
  const int k0 = by * 32, n0 = bx * 32;
  const int tx = threadIdx.x & 31, ty = threadIdx.x >> 5;
  #pragma unroll
  for (int i = 0; i < 4; i++) {
    int r = ty + i * 8;
    tile[r][tx] = f2bf(W[(int64_t)(k0 + r) * N + n0 + tx]);
  }
  __syncthreads();
  #pragma unroll
  for (int i = 0; i < 4; i++) {
    int r = ty + i * 8;
    Wt[(int64_t)(n0 + r) * K + k0 + tx] = tile[tx][r];
  }
}

// ---------------- per-head transpose: qkv[b][s][h*64+d] -> qkvT[b][h][d][s] --
__global__ __launch_bounds__(256)
void qkvt_kernel(const unsigned short* __restrict__ qkv,
                 unsigned short* __restrict__ qkvT) {
  __shared__ unsigned short tile[32][33];
  const int s0 = blockIdx.x * 32, d0 = blockIdx.y * 32, bh = blockIdx.z;
  const int b = bh >> 4, h = bh & 15;
  const int tx = threadIdx.x & 31, ty = threadIdx.x >> 5;
  #pragma unroll
  for (int i = 0; i < 4; i++) {
    int r = ty + i * 8;
    tile[r][tx] = qkv[(int64_t)(b * S_LEN + s0 + r) * D_MODEL + h * DK + d0 + tx];
  }
  __syncthreads();
  #pragma unroll
  for (int i = 0; i < 4; i++) {
    int r = ty + i * 8;
    qkvT[(int64_t)(bh * DK + d0 + r) * S_LEN + s0 + tx] = tile[tx][r];
  }
}

// ---------------- mask pre-layout: int32 [B,S,S] -> bf16 fragment table -------
__global__ __launch_bounds__(256)
void mprep_kernel(const int* __restrict__ mask, unsigned short* __restrict__ Mf) {
  const int gid = blockIdx.x * 256 + threadIdx.x;   // 262144 total
  const int lo = gid & 15;
  const int ktb = (gid >> 4) & 31;
  const int q4 = (gid >> 9) & 255;
  const int b = gid >> 17;
  const int* mrow = mask + ((int64_t)b << 20) + (int64_t)q4 * 4096 + ktb * 32 + lo;
  union { unsigned short us[8]; short8 v; } o;
  #pragma unroll
  for (int r = 0; r < 4; r++) {
    o.us[r * 2]     = mrow[r * 1024]      ? 0x3F80 : 0;
    o.us[r * 2 + 1] = mrow[r * 1024 + 16] ? 0x3F80 : 0;
  }
  ((short8*)Mf)[gid] = o.v;
}

// ======== gemm_ks: 64x64 tile, 4 waves SPLIT K (each full tile, K/4 slice) ===
// BK=128/step; wave w covers k subrange [w*32, w*32+32). dbuf prefetch.
template<int BIAS, int RELU, int RES, int OUTBF>
__global__ __launch_bounds__(256)
void gemm_ks(const unsigned short* __restrict__ A,
             const unsigned short* __restrict__ Bt,
             const float* __restrict__ bias,
             const float* __restrict__ res,
             void* __restrict__ outp,
             int M, int N, int K) {
  __shared__ __align__(16) unsigned short As[2][8192];  // 64 x 128
  __shared__ __align__(16) unsigned short Bs[2][8192];
  const int tid = threadIdx.x;
  const int lane = tid & 63;
  const int wave = tid >> 6;
  const int lo = lane & 15, hi = lane >> 4;

  const int cpx = gridDim.x >> 3;
  const int sid = (blockIdx.x & 7) * cpx + (blockIdx.x >> 3);
  const int nbx = N >> 6;
  const int n0 = (sid % nbx) << 6;
  const int m0 = (sid / nbx) << 6;

  // staging: 4 rounds x (4 rows/wave); row = r*16 + wave*4 + sr
  const int sr = lane >> 4;            // lane/16
  const int sc = lane & 15;            // 16B chunk
  const int srow = wave * 4 + sr;
  const int sch = (sc ^ (srow & 7)) * 8;
  const unsigned short* Ag = A + (int64_t)(m0 + srow) * K + sch;
  const unsigned short* Bg = Bt + (int64_t)(n0 + srow) * K + sch;

  // read side: row = t*16 + lo; chunk = (wave*4 + hi) ^ (row&7)
  const int rch = ((wave * 4 + hi) ^ (lo & 7)) * 8;

  f32x4 acc[4][4] = {};
  const int NT = K >> 7;

  auto stage = [&](int buf, int k0) {
    #pragma unroll
    for (int r = 0; r < 4; r++)
      gll16(Ag + (int64_t)r * 16 * K + k0, &As[buf][r * 2048 + wave * 512]);
    #pragma unroll
    for (int r = 0; r < 4; r++)
      gll16(Bg + (int64_t)r * 16 * K + k0, &Bs[buf][r * 2048 + wave * 512]);
  };

  stage(0, 0);
  __syncthreads();
  int cur = 0;
  for (int t = 0; t < NT; t++) {
    if (t + 1 < NT) stage(cur ^ 1, (t + 1) << 7);
    short8 af[4], bf[4];
    #pragma unroll
    for (int q = 0; q < 4; q++) {
      af[q] = *(const short8*)&As[cur][(q * 16 + lo) * 128 + rch];
      bf[q] = *(const short8*)&Bs[cur][(q * 16 + lo) * 128 + rch];
    }
    #pragma unroll
    for (int i = 0; i < 4; i++)
      #pragma unroll
      for (int j = 0; j < 4; j++)
        acc[i][j] = __builtin_amdgcn_mfma_f32_16x16x32_bf16(af[i], bf[j], acc[i][j], 0, 0, 0);
    __syncthreads();
    cur ^= 1;
  }

  // ---- cross-wave K-reduction through LDS (As region, 32 KB = 8192 f32) ----
  float* red = (float*)&As[0][0];
  if (wave >= 2) {
    #pragma unroll
    for (int i = 0; i < 4; i++)
      #pragma unroll
      for (int j = 0; j < 4; j++)
        *(f32x4*)&red[(wave - 2) * 4096 + (i * 4 + j) * 256 + lane * 4] = acc[i][j];
  }
  __syncthreads();
  if (wave < 2) {
    #pragma unroll
    for (int i = 0; i < 4; i++)
      #pragma unroll
      for (int j = 0; j < 4; j++)
        acc[i][j] += *(const f32x4*)&red[wave * 4096 + (i * 4 + j) * 256 + lane * 4];
  }
  __syncthreads();
  if (wave == 0) {
    #pragma unroll
    for (int i = 2; i < 4; i++)
      #pragma unroll
      for (int j = 0; j < 4; j++)
        *(f32x4*)&red[((i - 2) * 4 + j) * 256 + lane * 4] = acc[i][j];
  } else if (wave == 1) {
    #pragma unroll
    for (int i = 0; i < 2; i++)
      #pragma unroll
      for (int j = 0; j < 4; j++)
        *(f32x4*)&red[2048 + (i * 4 + j) * 256 + lane * 4] = acc[i][j];
  }
  __syncthreads();

  if (wave < 2) {
    const int ib = wave * 2;   // wave0 -> rows 0..31 (i=0,1); wave1 -> 32..63 (i=2,3)
    #pragma unroll
    for (int ii = 0; ii < 2; ii++) {
      const int i = ib + ii;
      #pragma unroll
      for (int j = 0; j < 4; j++) {
        f32x4 v4 = acc[i][j];
        v4 += *(const f32x4*)&red[(wave ? (ii * 4 + j) * 256 : 2048 + (i * 4 + j) * 256) + lane * 4];
        const int row = m0 + i * 16 + hi * 4;
        const int col = n0 + j * 16 + lo;
        #pragma unroll
        for (int r = 0; r < 4; r++) {
          float v = v4[r];
          if (BIAS) v += bias[col];
          if (RELU) v = fmaxf(v, 0.f);
          if (RES)  v += res[(int64_t)(row + r) * N + col];
          if (OUTBF)
            ((unsigned short*)outp)[(int64_t)(row + r) * N + col] = f2bf(v);
          else
            ((float*)outp)[(int64_t)(row + r) * N + col] = v;
        }
      }
    }
  }
}

// ======== gemm_ffn1: 128x128 tile, 4 waves (64x64 each), BK=64, dbuf =========
// out = bf16(relu(A @ Bt^T + bias))
__global__ __launch_bounds__(256)
void gemm_ffn1(const unsigned short* __restrict__ A,
               const unsigned short* __restrict__ Bt,
               const float* __restrict__ bias,
               unsigned short* __restrict__ outp,
               int M, int N, int K) {
  __shared__ __align__(16) unsigned short As[2][8192];  // 128 x 64
  __shared__ __align__(16) unsigned short Bs[2][8192];
  const int tid = threadIdx.x;
  const int lane = tid & 63;
  const int wave = tid >> 6;
  const int lo = lane & 15, hi = lane >> 4;

  const int cpx = gridDim.x >> 3;
  const int sid = (blockIdx.x & 7) * cpx + (blockIdx.x >> 3);
  const int nbx = N >> 7;
  const int n0 = (sid % nbx) << 7;
  const int m0 = (sid / nbx) << 7;
  const int wr = (wave >> 1) * 64;
  const int wc = (wave & 1) * 64;

  // staging: rows r*32 + wave*8 + sr; sr = lane/8, sc = lane%8; swz c ^ (row&7)
  const int sr = lane >> 3;
  const int sc = lane & 7;
  const int srow = wave * 8 + sr;
  const int sch = (sc ^ (srow & 7)) * 8;
  const unsigned short* Ag = A + (int64_t)(m0 + srow) * K + sch;
  const unsigned short* Bg = Bt + (int64_t)(n0 + srow) * K + sch;

  const int xr = lo & 7;   // read-side row&7

  f32x4 acc[4][4] = {};
  const int NT = K >> 6;

  auto stage = [&](int buf, int k0) {
    #pragma unroll
    for (int r = 0; r < 4; r++)
      gll16(Ag + (int64_t)r * 32 * K + k0, &As[buf][r * 2048 + wave * 512]);
    #pragma unroll
    for (int r = 0; r < 4; r++)
      gll16(Bg + (int64_t)r * 32 * K + k0, &Bs[buf][r * 2048 + wave * 512]);
  };

  stage(0, 0);
  __syncthreads();
  int cur = 0;
  for (int t = 0; t < NT; t++) {
    if (t + 1 < NT) stage(cur ^ 1, (t + 1) << 6);
    #pragma unroll
    for (int kk = 0; kk < 2; kk++) {
      short8 af[4], bf[4];
      const int ch = ((kk * 4 + hi) ^ xr) * 8;
      #pragma unroll
      for (int q = 0; q < 4; q++) {
        af[q] = *(const short8*)&As[cur][(wr + q * 16 + lo) * 64 + ch];
        bf[q] = *(const short8*)&Bs[cur][(wc + q * 16 + lo) * 64 + ch];
      }
      #pragma unroll
      for (int i = 0; i < 4; i++)
        #pragma unroll
        for (int j = 0; j < 4; j++)
          acc[i][j] = __builtin_amdgcn_mfma_f32_16x16x32_bf16(af[i], bf[j], acc[i][j], 0, 0, 0);
    }
    __syncthreads();
    cur ^= 1;
  }

  #pragma unroll
  for (int i = 0; i < 4; i++) {
    const int row = m0 + wr + i * 16 + hi * 4;
    #pragma unroll
    for (int j = 0; j < 4; j++) {
      const int col = n0 + wc + j * 16 + lo;
      const float bv = bias[col];
      #pragma unroll
      for (int r = 0; r < 4; r++) {
        float v = fmaxf(acc[i][j][r] + bv, 0.f);
        outp[(int64_t)(row + r) * N + col] = f2bf(v);
      }
    }
  }
}

// -------- fused attention: LDS-staged K/V/M tiles, KV-split x2, XCD-local ----
__global__ __launch_bounds__(256)
void attn_kernel(const unsigned short* __restrict__ qkv,
                 const unsigned short* __restrict__ qkvT,
                 const unsigned short* __restrict__ Mf,
                 float* __restrict__ part,
                 float* __restrict__ psum) {
  __shared__ __align__(16) unsigned short Ks[64 * 64];
  __shared__ __align__(16) unsigned short Vs[64 * 64];
  __shared__ __align__(16) unsigned short Ms[512 * 8];
  __shared__ __align__(16) unsigned short Plds[4][16 * 40];
  const int tid = threadIdx.x;
  const int lane = tid & 63;
  const int wave = tid >> 6;
  const int lo = lane & 15, hi = lane >> 4;
  const int L = blockIdx.x;            // 1024 blocks
  const int xcd = L & 7, idx = L >> 3;
  const int b = xcd >> 2;
  const int h = (xcd & 3) * 4 + (idx >> 5);
  const int split = (idx >> 4) & 1;
  const int qt = idx & 15;
  const int bh = b * 16 + h;
  const int q0 = qt * 64 + wave * 16;

  const unsigned short* qb =
      qkv + (int64_t)(b * S_LEN + q0 + lo) * D_MODEL + h * DK + hi * 8;
  const short8 qf0 = *(const short8*)qb;
  const short8 qf1 = *(const short8*)(qb + 32);

  f32x4 oacc[4] = {};
  float rsum[4] = {0.f, 0.f, 0.f, 0.f};
  unsigned short* Pw = Plds[wave];
  const int kbeg = split * 512;
  const int q4w = wave * 4 + hi;
  const int xr = lo & 7;

  for (int kti = 0; kti < 8; kti++) {
    const int kt = kbeg + kti * 64;
    #pragma unroll
    for (int r = 0; r < 2; r++) {
      const int c = r * 256 + tid;
      const int row = c >> 3;
      const int chg = (c & 7) ^ (row & 7);
      gll16(qkv + (int64_t)(b * S_LEN + kt + row) * D_MODEL + h * DK + chg * 8,
            &Ks[(r * 256 + wave * 64) * 8]);
      gll16(qkvT + (int64_t)(bh * DK + row) * S_LEN + kt + chg * 8,
            &Vs[(r * 256 + wave * 64) * 8]);
      const int q4l = c >> 5;
      const int u2 = (c >> 4) & 1;
      const int log = (c & 15) ^ q4l;
      gll16(Mf + ((int64_t)((b * 256 + qt * 16 + q4l) * 32 + (kt >> 5) + u2) * 16 + log) * 8,
            &Ms[(r * 256 + wave * 64) * 8]);
    }
    __syncthreads();
    #pragma unroll
    for (int u = 0; u < 2; u++) {
      const short8 kf00 = *(const short8*)&Ks[((u * 32 + lo) * 8 + (hi ^ xr)) * 8];
      const short8 kf01 = *(const short8*)&Ks[((u * 32 + lo) * 8 + ((4 + hi) ^ xr)) * 8];
      const short8 kf10 = *(const short8*)&Ks[((u * 32 + 16 + lo) * 8 + (hi ^ xr)) * 8];
      const short8 kf11 = *(const short8*)&Ks[((u * 32 + 16 + lo) * 8 + ((4 + hi) ^ xr)) * 8];
      const short8 mf = *(const short8*)&Ms[(q4w * 32 + u * 16 + (lo ^ q4w)) * 8];
      f32x4 s0 = {}, s1 = {};
      s0 = __builtin_amdgcn_mfma_f32_16x16x32_bf16(qf0, kf00, s0, 0, 0, 0);
      s0 = __builtin_amdgcn_mfma_f32_16x16x32_bf16(qf1, kf01, s0, 0, 0, 0);
      s1 = __builtin_amdgcn_mfma_f32_16x16x32_bf16(qf0, kf10, s1, 0, 0, 0);
      s1 = __builtin_amdgcn_mfma_f32_16x16x32_bf16(qf1, kf11, s1, 0, 0, 0);
      #pragma unroll
      for (int r = 0; r < 4; r++) {
        const float m0_ = bf2f((unsigned short)mf[r * 2]);
        const float m1_ = bf2f((unsigned short)mf[r * 2 + 1]);
        const float e0_ = __expf(s0[r] * 0.125f);
        const float e1_ = __expf(s1[r] * 0.125f);
        const float p0_ = fmaf(m0_, e0_ - 1.f, 1.f);
        const float p1_ = fmaf(m1_, e1_ - 1.f, 1.f);
        rsum[r] += p0_ + p1_;
        Pw[(hi * 4 + r) * 40 + lo]      = f2bf(p0_);
        Pw[(hi * 4 + r) * 40 + 16 + lo] = f2bf(p1_);
      }
      const short8 pf = *(const short8*)&Pw[lo * 40 + hi * 8];
      #pragma unroll
      for (int t = 0; t < 4; t++) {
        const short8 vf = *(const short8*)&Vs[((t * 16 + lo) * 8 + ((u * 4 + hi) ^ xr)) * 8];
        oacc[t] = __builtin_amdgcn_mfma_f32_16x16x32_bf16(pf, vf, oacc[t], 0, 0, 0);
      }
    }
    __syncthreads();
  }

  #pragma unroll
  for (int m = 1; m < 16; m <<= 1)
    #pragma unroll
    for (int r = 0; r < 4; r++) rsum[r] += __shfl_xor(rsum[r], m);

  const int64_t prow = (int64_t)(split * 32 + bh) * 1024;
  #pragma unroll
  for (int t = 0; t < 4; t++)
    #pragma unroll
    for (int r = 0; r < 4; r++)
      part[(prow + q0 + hi * 4 + r) * 64 + t * 16 + lo] = oacc[t][r];
  if (lo == 0)
    #pragma unroll
    for (int r = 0; r < 4; r++)
      psum[prow + q0 + hi * 4 + r] = rsum[r];
}

// ---------------- combine KV-split partials -> ctx (bf16) --------------------
__global__ __launch_bounds__(256)
void acomb_kernel(const float* __restrict__ part,
                  const float* __restrict__ psum,
                  unsigned short* __restrict__ ctx) {
  const int idx4 = blockIdx.x * 256 + threadIdx.x;   // 524288
  const int d4 = idx4 & 15;
  const int q = (idx4 >> 4) & 1023;
  const int bh = idx4 >> 14;
  const int b = bh >> 4, h = bh & 15;
  const float4* p4 = (const float4*)part;
  const float4 a0 = p4[(int64_t)(bh * 1024 + q) * 16 + d4];
  const float4 a1 = p4[524288 + (int64_t)(bh * 1024 + q) * 16 + d4];
  const float rs = psum[bh * 1024 + q] + psum[32768 + bh * 1024 + q];
  const float inv = 1.f / rs;
  union { unsigned short us[4]; uint2 u2; } pk;
  pk.us[0] = f2bf((a0.x + a1.x) * inv);
  pk.us[1] = f2bf((a0.y + a1.y) * inv);
  pk.us[2] = f2bf((a0.z + a1.z) * inv);
  pk.us[3] = f2bf((a0.w + a1.w) * inv);
  *(uint2*)(ctx + (int64_t)(b * S_LEN + q) * D_MODEL + h * DK + d4 * 4) = pk.u2;
}

// -----------------------------------------------------------------------------
extern "C" void kernel_launch(void* const* d_in, const int* in_sizes, int n_in,
                              void* d_out, int out_size, void* d_ws, size_t ws_size,
                              hipStream_t stream) {
  (void)in_sizes; (void)n_in; (void)out_size; (void)ws_size;
  const float* x    = (const float*)d_in[0];
  const int*   mask = (const int*)d_in[1];
  const float* Wq   = (const float*)d_in[2];
  const float* Wo   = (const float*)d_in[3];
  const float* W1   = (const float*)d_in[4];
  const float* B1   = (const float*)d_in[5];
  const float* W2   = (const float*)d_in[6];
  const float* B2   = (const float*)d_in[7];
  const float* ln1a = (const float*)d_in[8];
  const float* ln1b = (const float*)d_in[9];
  const float* ln2a = (const float*)d_in[10];
  const float* ln2b = (const float*)d_in[11];
  float* out = (float*)d_out;

  char* ws = (char*)d_ws;
  unsigned short* WqT  = (unsigned short*)(ws);                     // [0,2) MB
  unsigned short* WoT  = (unsigned short*)(ws + (2ull  << 20));     // [2,4)
  unsigned short* W1T  = (unsigned short*)(ws + (4ull  << 20));     // [4,12)
  unsigned short* W2T  = (unsigned short*)(ws + (12ull << 20));     // [12,20)
  unsigned short* n1   = (unsigned short*)(ws + (20ull << 20));     // [20,24)
  float*          psum = (float*)(ws + (20ull << 20));              // reuses n1
  unsigned short* qkv  = (unsigned short*)(ws + (24ull << 20));     // [24,28)
  unsigned short* qkvT = (unsigned short*)(ws + (28ull << 20));     // [28,32)
  unsigned short* Mf   = (unsigned short*)(ws + (32ull << 20));     // [32,36)
  unsigned short* ctx  = (unsigned short*)(ws + (32ull << 20));     // [32,36)
  unsigned short* n2   = (unsigned short*)(ws + (36ull << 20));     // [36,40)
  float*          part = (float*)(ws + (40ull << 20));              // [40,56)
  unsigned short* h1   = (unsigned short*)(ws + (40ull << 20));     // [40,56)
  float* x1 = out;  // residual-1 result lives in d_out (fully rewritten later)

  dim3 blk(256);
  wtall_kernel<<<10240, blk, 0, stream>>>(Wq, Wo, W1, W2, WqT, WoT, W1T, W2T);
  mprep_kernel<<<1024, blk, 0, stream>>>(mask, Mf);

  ln_kernel<<<2048, blk, 0, stream>>>(x, ln1a, ln1b, n1);
  gemm_ks<0,0,0,1><<<512, blk, 0, stream>>>(n1, WqT, nullptr, nullptr, qkv, 2048, 1024, 1024);
  qkvt_kernel<<<dim3(32, 2, 32), blk, 0, stream>>>(qkv, qkvT);
  attn_kernel<<<1024, blk, 0, stream>>>(qkv, qkvT, Mf, part, psum);
  acomb_kernel<<<2048, blk, 0, stream>>>(part, psum, ctx);
  gemm_ks<0,0,1,0><<<512, blk, 0, stream>>>(ctx, WoT, nullptr, x, x1, 2048, 1024, 1024);
  ln_kernel<<<2048, blk, 0, stream>>>(x1, ln2a, ln2b, n2);
  gemm_ffn1<<<512, blk, 0, stream>>>(n2, W1T, B1, h1, 2048, 4096, 1024);
  gemm_ks<1,0,1,0><<<512, blk, 0, stream>>>(h1, W2T, B2, x1, out, 2048, 1024, 4096);
}

// Round 8
// 166.059 us; speedup vs baseline: 2.9838x; 2.9838x over previous
//
#include <hip/hip_runtime.h>
#include <hip/hip_bf16.h>
#include <stdint.h>

#define D_MODEL 1024
#define S_LEN 1024
#define BATCH 2
#define NHEADS 16
#define DK 64
#define DFF 4096

typedef __attribute__((ext_vector_type(8))) short short8;
typedef __attribute__((ext_vector_type(4))) float f32x4;

__device__ __forceinline__ unsigned short f2bf(float f) {
  union { float f; unsigned u; } v; v.f = f;
  unsigned r = v.u + 0x7FFFu + ((v.u >> 16) & 1u);
  return (unsigned short)(r >> 16);
}

__device__ __forceinline__ float bf2f(unsigned short s) {
  union { float f; unsigned u; } v; v.u = ((unsigned)s) << 16;
  return v.f;
}

__device__ __forceinline__ void gll16(const void* g, void* l) {
  __builtin_amdgcn_global_load_lds(
      (const __attribute__((address_space(1))) void*)g,
      (__attribute__((address_space(3))) void*)l, 16, 0, 0);
}

// ---------------- LayerNorm: f32 in -> bf16 out (ddof=1 std per reference) ----
__global__ __launch_bounds__(256)
void ln_kernel(const float* __restrict__ x,
               const float* __restrict__ alpha,
               const float* __restrict__ beta,
               unsigned short* __restrict__ out) {
  const int row = blockIdx.x;
  const int tid = threadIdx.x;
  const float4 v = ((const float4*)(x + (int64_t)row * D_MODEL))[tid];
  float s = v.x + v.y + v.z + v.w;
  float ss = v.x * v.x + v.y * v.y + v.z * v.z + v.w * v.w;
  #pragma unroll
  for (int m = 32; m; m >>= 1) {
    s += __shfl_down(s, m);
    ss += __shfl_down(ss, m);
  }
  __shared__ float red[10];
  const int wave = tid >> 6;
  if ((tid & 63) == 0) { red[wave] = s; red[4 + wave] = ss; }
  __syncthreads();
  if (tid == 0) {
    float S = red[0] + red[1] + red[2] + red[3];
    float SS = red[4] + red[5] + red[6] + red[7];
    float mean = S * (1.f / 1024.f);
    float var = (SS - 1024.f * mean * mean) * (1.f / 1023.f);
    float inv = 1.f / (sqrtf(fmaxf(var, 0.f)) + 1e-6f);
    red[8] = mean; red[9] = inv;
  }
  __syncthreads();
  const float mean = red[8], inv = red[9];
  const float4 a = ((const float4*)alpha)[tid];
  const float4 bb = ((const float4*)beta)[tid];
  union { unsigned short us[4]; uint2 u2; } pk;
  pk.us[0] = f2bf(a.x * (v.x - mean) * inv + bb.x);
  pk.us[1] = f2bf(a.y * (v.y - mean) * inv + bb.y);
  pk.us[2] = f2bf(a.z * (v.z - mean) * inv + bb.z);
  pk.us[3] = f2bf(a.w * (v.w - mean) * inv + bb.w);
  ((uint2*)(out + (int64_t)row * D_MODEL))[tid] = pk.u2;
}

// ---------------- All four weight transposes in ONE launch -------------------
__global__ __launch_bounds__(256)
void wtall_kernel(const float* __restrict__ Wq, const float* __restrict__ Wo,
                  const float* __restrict__ W1, const float* __restrict__ W2,
                  unsigned short* __restrict__ WqT, unsigned short* __restrict__ WoT,
                  unsigned short* __restrict__ W1T, unsigned short* __restrict__ W2T) {
  __shared__ unsigned short tile[32][33];
  int id = blockIdx.x;
  const float* W; unsigned short* Wt; int K, N, bx, by;
  if (id < 1024)      { W = Wq; Wt = WqT; K = 1024; N = 1024; bx = id & 31;  by = id >> 5; }
  else if (id < 2048) { id -= 1024; W = Wo; Wt = WoT; K = 1024; N = 1024; bx = id & 31;  by = id >> 5; }
  else if (id < 6144) { id -= 2048; W = W1; Wt = W1T; K = 1024; N = 4096; bx = id & 127; by = id >> 7; }
  else                { id -= 6144; W = W2; Wt = W2T; K = 4096; N = 1024; bx = id & 31;  by = id >> 5; }
  const int k0 = by * 32, n0 = bx * 32;
  const int tx = threadIdx.x & 31, ty = threadIdx.x >> 5;
  #pragma unroll
  for (int i = 0; i < 4; i++) {
    int r = ty + i * 8;
    tile[r][tx] = f2bf(W[(int64_t)(k0 + r) * N + n0 + tx]);
  }
  __syncthreads();
  #pragma unroll
  for (int i = 0; i < 4; i++) {
    int r = ty + i * 8;
    Wt[(int64_t)(n0 + r) * K + k0 + tx] = tile[tx][r];
  }
}

// ---------------- per-head transpose: qkv[b][s][h*64+d] -> qkvT[b][h][d][s] --
__global__ __launch_bounds__(256)
void qkvt_kernel(const unsigned short* __restrict__ qkv,
                 unsigned short* __restrict__ qkvT) {
  __shared__ unsigned short tile[32][33];
  const int s0 = blockIdx.x * 32, d0 = blockIdx.y * 32, bh = blockIdx.z;
  const int b = bh >> 4, h = bh & 15;
  const int tx = threadIdx.x & 31, ty = threadIdx.x >> 5;
  #pragma unroll
  for (int i = 0; i < 4; i++) {
    int r = ty + i * 8;
    tile[r][tx] = qkv[(int64_t)(b * S_LEN + s0 + r) * D_MODEL + h * DK + d0 + tx];
  }
  __syncthreads();
  #pragma unroll
  for (int i = 0; i < 4; i++) {
    int r = ty + i * 8;
    qkvT[(int64_t)(bh * DK + d0 + r) * S_LEN + s0 + tx] = tile[tx][r];
  }
}

// ---------------- mask pre-layout: int32 [B,S,S] -> bf16 fragment table -------
__global__ __launch_bounds__(256)
void mprep_kernel(const int* __restrict__ mask, unsigned short* __restrict__ Mf) {
  const int gid = blockIdx.x * 256 + threadIdx.x;   // 262144 total
  const int lo = gid & 15;
  const int ktb = (gid >> 4) & 31;
  const int q4 = (gid >> 9) & 255;
  const int b = gid >> 17;
  const int* mrow = mask + ((int64_t)b << 20) + (int64_t)q4 * 4096 + ktb * 32 + lo;
  union { unsigned short us[8]; short8 v; } o;
  #pragma unroll
  for (int r = 0; r < 4; r++) {
    o.us[r * 2]     = mrow[r * 1024]      ? 0x3F80 : 0;
    o.us[r * 2 + 1] = mrow[r * 1024 + 16] ? 0x3F80 : 0;
  }
  ((short8*)Mf)[gid] = o.v;
}

// ======== gemm_db: round-6 gemm_t + static-ping-pong 2-phase prefetch ========
// Waves tile 2x2 (each BM/2 x BN/2). LDS = 2*(BM+BN)*BK*2 bytes (32 KB at the
// chosen shapes). Buffer names are compile-time (no dynamic cur -> no spill).
template<int BM, int BN, int BK, int BIAS, int RELU, int RES, int OUTBF>
__global__ __launch_bounds__(256)
void gemm_db(const unsigned short* __restrict__ A,
             const unsigned short* __restrict__ Bt,
             const float* __restrict__ bias,
             const float* __restrict__ res,
             void* __restrict__ outp,
             int M, int N, int K) {
  constexpr int NCH = BK / 8;              // 16B chunks per row
  constexpr int RA = (BM * BK) / 2048;     // staging rounds for A (256 thr)
  constexpr int RB = (BN * BK) / 2048;
  constexpr int MI = BM / 32;
  constexpr int NJ = BN / 32;
  constexpr int KK = BK / 32;

  __shared__ __align__(16) unsigned short As[2][BM * BK];
  __shared__ __align__(16) unsigned short Bs[2][BN * BK];

  const int tid = threadIdx.x;
  const int lane = tid & 63;
  const int wave = tid >> 6;
  const int lo = lane & 15, hi = lane >> 4;

  const int cpx = gridDim.x >> 3;
  const int sid = (blockIdx.x & 7) * cpx + (blockIdx.x >> 3);
  const int nbx = N / BN;
  const int n0 = (sid % nbx) * BN;
  const int m0 = (sid / nbx) * BM;
  const int wr = (wave >> 1) * (BM / 2);
  const int wc = (wave & 1) * (BN / 2);

  auto swz = [](int row, int c) -> int {
    if (BK >= 64) return c ^ (row & 7);
    return c ^ ((row >> 1) & 3);   // BK == 32
  };

  // per-lane staging source pointers (row/chunk fixed per r; k0 added later)
  const unsigned short* Ap[RA];
  const unsigned short* Bp[RB];
  #pragma unroll
  for (int r = 0; r < RA; r++) {
    const int c = r * 256 + tid;
    const int row = c / NCH, sc = c % NCH;
    Ap[r] = A + (int64_t)(m0 + row) * K + swz(row, sc) * 8;
  }
  #pragma unroll
  for (int r = 0; r < RB; r++) {
    const int c = r * 256 + tid;
    const int row = c / NCH, sc = c % NCH;
    Bp[r] = Bt + (int64_t)(n0 + row) * K + swz(row, sc) * 8;
  }

  f32x4 acc[MI][NJ] = {};
  const int NT = K / BK;                   // always even here (16/32/64)

  auto stage = [&](unsigned short* Al, unsigned short* Bl, int k0) {
    #pragma unroll
    for (int r = 0; r < RA; r++)
      gll16(Ap[r] + k0, Al + (r * 256 + wave * 64) * 8);
    #pragma unroll
    for (int r = 0; r < RB; r++)
      gll16(Bp[r] + k0, Bl + (r * 256 + wave * 64) * 8);
  };

  auto compute = [&](const unsigned short* Al, const unsigned short* Bl) {
    #pragma unroll
    for (int kk = 0; kk < KK; kk++) {
      short8 af[MI], bf[NJ];
      #pragma unroll
      for (int t = 0; t < MI; t++) {
        const int row = wr + t * 16 + lo;
        af[t] = *(const short8*)&Al[row * BK + swz(row, kk * 4 + hi) * 8];
      }
      #pragma unroll
      for (int t = 0; t < NJ; t++) {
        const int row = wc + t * 16 + lo;
        bf[t] = *(const short8*)&Bl[row * BK + swz(row, kk * 4 + hi) * 8];
      }
      #pragma unroll
      for (int i = 0; i < MI; i++)
        #pragma unroll
        for (int j = 0; j < NJ; j++)
          acc[i][j] = __builtin_amdgcn_mfma_f32_16x16x32_bf16(af[i], bf[j], acc[i][j], 0, 0, 0);
    }
  };

  unsigned short* A0 = &As[0][0]; unsigned short* B0 = &Bs[0][0];
  unsigned short* A1 = &As[1][0]; unsigned short* B1 = &Bs[1][0];

  stage(A0, B0, 0);
  __syncthreads();
  for (int t = 0; t < NT; t += 2) {
    stage(A1, B1, (t + 1) * BK);       // prefetch next (always valid: NT even)
    compute(A0, B0);
    __syncthreads();                   // buf1 ready; buf0 free
    if (t + 2 < NT) stage(A0, B0, (t + 2) * BK);
    compute(A1, B1);
    __syncthreads();
  }

  #pragma unroll
  for (int i = 0; i < MI; i++) {
    const int row = m0 + wr + i * 16 + hi * 4;
    #pragma unroll
    for (int j = 0; j < NJ; j++) {
      const int col = n0 + wc + j * 16 + lo;
      #pragma unroll
      for (int r = 0; r < 4; r++) {
        float v = acc[i][j][r];
        if (BIAS) v += bias[col];
        if (RELU) v = fmaxf(v, 0.f);
        if (RES)  v += res[(int64_t)(row + r) * N + col];
        if (OUTBF)
          ((unsigned short*)outp)[(int64_t)(row + r) * N + col] = f2bf(v);
        else
          ((float*)outp)[(int64_t)(row + r) * N + col] = v;
      }
    }
  }
}

// -------- fused attention: LDS-staged K/V/M tiles, KV-split x2, XCD-local ----
__global__ __launch_bounds__(256)
void attn_kernel(const unsigned short* __restrict__ qkv,
                 const unsigned short* __restrict__ qkvT,
                 const unsigned short* __restrict__ Mf,
                 float* __restrict__ part,
                 float* __restrict__ psum) {
  __shared__ __align__(16) unsigned short Ks[64 * 64];
  __shared__ __align__(16) unsigned short Vs[64 * 64];
  __shared__ __align__(16) unsigned short Ms[512 * 8];
  __shared__ __align__(16) unsigned short Plds[4][16 * 40];
  const int tid = threadIdx.x;
  const int lane = tid & 63;
  const int wave = tid >> 6;
  const int lo = lane & 15, hi = lane >> 4;
  const int L = blockIdx.x;            // 1024 blocks
  const int xcd = L & 7, idx = L >> 3;
  const int b = xcd >> 2;
  const int h = (xcd & 3) * 4 + (idx >> 5);
  const int split = (idx >> 4) & 1;
  const int qt = idx & 15;
  const int bh = b * 16 + h;
  const int q0 = qt * 64 + wave * 16;

  const unsigned short* qb =
      qkv + (int64_t)(b * S_LEN + q0 + lo) * D_MODEL + h * DK + hi * 8;
  const short8 qf0 = *(const short8*)qb;
  const short8 qf1 = *(const short8*)(qb + 32);

  f32x4 oacc[4] = {};
  float rsum[4] = {0.f, 0.f, 0.f, 0.f};
  unsigned short* Pw = Plds[wave];
  const int kbeg = split * 512;
  const int q4w = wave * 4 + hi;
  const int xr = lo & 7;

  for (int kti = 0; kti < 8; kti++) {
    const int kt = kbeg + kti * 64;
    #pragma unroll
    for (int r = 0; r < 2; r++) {
      const int c = r * 256 + tid;
      const int row = c >> 3;
      const int chg = (c & 7) ^ (row & 7);
      gll16(qkv + (int64_t)(b * S_LEN + kt + row) * D_MODEL + h * DK + chg * 8,
            &Ks[(r * 256 + wave * 64) * 8]);
      gll16(qkvT + (int64_t)(bh * DK + row) * S_LEN + kt + chg * 8,
            &Vs[(r * 256 + wave * 64) * 8]);
      const int q4l = c >> 5;
      const int u2 = (c >> 4) & 1;
      const int log = (c & 15) ^ q4l;
      gll16(Mf + ((int64_t)((b * 256 + qt * 16 + q4l) * 32 + (kt >> 5) + u2) * 16 + log) * 8,
            &Ms[(r * 256 + wave * 64) * 8]);
    }
    __syncthreads();
    #pragma unroll
    for (int u = 0; u < 2; u++) {
      const short8 kf00 = *(const short8*)&Ks[((u * 32 + lo) * 8 + (hi ^ xr)) * 8];
      const short8 kf01 = *(const short8*)&Ks[((u * 32 + lo) * 8 + ((4 + hi) ^ xr)) * 8];
      const short8 kf10 = *(const short8*)&Ks[((u * 32 + 16 + lo) * 8 + (hi ^ xr)) * 8];
      const short8 kf11 = *(const short8*)&Ks[((u * 32 + 16 + lo) * 8 + ((4 + hi) ^ xr)) * 8];
      const short8 mf = *(const short8*)&Ms[(q4w * 32 + u * 16 + (lo ^ q4w)) * 8];
      f32x4 s0 = {}, s1 = {};
      s0 = __builtin_amdgcn_mfma_f32_16x16x32_bf16(qf0, kf00, s0, 0, 0, 0);
      s0 = __builtin_amdgcn_mfma_f32_16x16x32_bf16(qf1, kf01, s0, 0, 0, 0);
      s1 = __builtin_amdgcn_mfma_f32_16x16x32_bf16(qf0, kf10, s1, 0, 0, 0);
      s1 = __builtin_amdgcn_mfma_f32_16x16x32_bf16(qf1, kf11, s1, 0, 0, 0);
      #pragma unroll
      for (int r = 0; r < 4; r++) {
        const float m0_ = bf2f((unsigned short)mf[r * 2]);
        const float m1_ = bf2f((unsigned short)mf[r * 2 + 1]);
        const float e0_ = __expf(s0[r] * 0.125f);
        const float e1_ = __expf(s1[r] * 0.125f);
        const float p0_ = fmaf(m0_, e0_ - 1.f, 1.f);
        const float p1_ = fmaf(m1_, e1_ - 1.f, 1.f);
        rsum[r] += p0_ + p1_;
        Pw[(hi * 4 + r) * 40 + lo]      = f2bf(p0_);
        Pw[(hi * 4 + r) * 40 + 16 + lo] = f2bf(p1_);
      }
      const short8 pf = *(const short8*)&Pw[lo * 40 + hi * 8];
      #pragma unroll
      for (int t = 0; t < 4; t++) {
        const short8 vf = *(const short8*)&Vs[((t * 16 + lo) * 8 + ((u * 4 + hi) ^ xr)) * 8];
        oacc[t] = __builtin_amdgcn_mfma_f32_16x16x32_bf16(pf, vf, oacc[t], 0, 0, 0);
      }
    }
    __syncthreads();
  }

  #pragma unroll
  for (int m = 1; m < 16; m <<= 1)
    #pragma unroll
    for (int r = 0; r < 4; r++) rsum[r] += __shfl_xor(rsum[r], m);

  const int64_t prow = (int64_t)(split * 32 + bh) * 1024;
  #pragma unroll
  for (int t = 0; t < 4; t++)
    #pragma unroll
    for (int r = 0; r < 4; r++)
      part[(prow + q0 + hi * 4 + r) * 64 + t * 16 + lo] = oacc[t][r];
  if (lo == 0)
    #pragma unroll
    for (int r = 0; r < 4; r++)
      psum[prow + q0 + hi * 4 + r] = rsum[r];
}

// ---------------- combine KV-split partials -> ctx (bf16) --------------------
__global__ __launch_bounds__(256)
void acomb_kernel(const float* __restrict__ part,
                  const float* __restrict__ psum,
                  unsigned short* __restrict__ ctx) {
  const int idx4 = blockIdx.x * 256 + threadIdx.x;   // 524288
  const int d4 = idx4 & 15;
  const int q = (idx4 >> 4) & 1023;
  const int bh = idx4 >> 14;
  const int b = bh >> 4, h = bh & 15;
  const float4* p4 = (const float4*)part;
  const float4 a0 = p4[(int64_t)(bh * 1024 + q) * 16 + d4];
  const float4 a1 = p4[524288 + (int64_t)(bh * 1024 + q) * 16 + d4];
  const float rs = psum[bh * 1024 + q] + psum[32768 + bh * 1024 + q];
  const float inv = 1.f / rs;
  union { unsigned short us[4]; uint2 u2; } pk;
  pk.us[0] = f2bf((a0.x + a1.x) * inv);
  pk.us[1] = f2bf((a0.y + a1.y) * inv);
  pk.us[2] = f2bf((a0.z + a1.z) * inv);
  pk.us[3] = f2bf((a0.w + a1.w) * inv);
  *(uint2*)(ctx + (int64_t)(b * S_LEN + q) * D_MODEL + h * DK + d4 * 4) = pk.u2;
}

// -----------------------------------------------------------------------------
extern "C" void kernel_launch(void* const* d_in, const int* in_sizes, int n_in,
                              void* d_out, int out_size, void* d_ws, size_t ws_size,
                              hipStream_t stream) {
  (void)in_sizes; (void)n_in; (void)out_size; (void)ws_size;
  const float* x    = (const float*)d_in[0];
  const int*   mask = (const int*)d_in[1];
  const float* Wq   = (const float*)d_in[2];
  const float* Wo   = (const float*)d_in[3];
  const float* W1   = (const float*)d_in[4];
  const float* B1   = (const float*)d_in[5];
  const float* W2   = (const float*)d_in[6];
  const float* B2   = (const float*)d_in[7];
  const float* ln1a = (const float*)d_in[8];
  const float* ln1b = (const float*)d_in[9];
  const float* ln2a = (const float*)d_in[10];
  const float* ln2b = (const float*)d_in[11];
  float* out = (float*)d_out;

  char* ws = (char*)d_ws;
  unsigned short* WqT  = (unsigned short*)(ws);                     // [0,2) MB
  unsigned short* WoT  = (unsigned short*)(ws + (2ull  << 20));     // [2,4)
  unsigned short* W1T  = (unsigned short*)(ws + (4ull  << 20));     // [4,12)
  unsigned short* W2T  = (unsigned short*)(ws + (12ull << 20));     // [12,20)
  unsigned short* n1   = (unsigned short*)(ws + (20ull << 20));     // [20,24)
  float*          psum = (float*)(ws + (20ull << 20));              // reuses n1
  unsigned short* qkv  = (unsigned short*)(ws + (24ull << 20));     // [24,28)
  unsigned short* qkvT = (unsigned short*)(ws + (28ull << 20));     // [28,32)
  unsigned short* Mf   = (unsigned short*)(ws + (32ull << 20));     // [32,36)
  unsigned short* ctx  = (unsigned short*)(ws + (32ull << 20));     // [32,36)
  unsigned short* n2   = (unsigned short*)(ws + (36ull << 20));     // [36,40)
  float*          part = (float*)(ws + (40ull << 20));              // [40,56)
  unsigned short* h1   = (unsigned short*)(ws + (40ull << 20));     // [40,56)
  float* x1 = out;  // residual-1 result lives in d_out (fully rewritten later)

  dim3 blk(256);
  wtall_kernel<<<10240, blk, 0, stream>>>(Wq, Wo, W1, W2, WqT, WoT, W1T, W2T);
  mprep_kernel<<<1024, blk, 0, stream>>>(mask, Mf);

  ln_kernel<<<2048, blk, 0, stream>>>(x, ln1a, ln1b, n1);
  gemm_db<64,64,64, 0,0,0,1><<<512, blk, 0, stream>>>(n1, WqT, nullptr, nullptr, qkv, 2048, 1024, 1024);
  qkvt_kernel<<<dim3(32, 2, 32), blk, 0, stream>>>(qkv, qkvT);
  attn_kernel<<<1024, blk, 0, stream>>>(qkv, qkvT, Mf, part, psum);
  acomb_kernel<<<2048, blk, 0, stream>>>(part, psum, ctx);
  gemm_db<64,64,64, 0,0,1,0><<<512, blk, 0, stream>>>(ctx, WoT, nullptr, x, x1, 2048, 1024, 1024);
  ln_kernel<<<2048, blk, 0, stream>>>(x1, ln2a, ln2b, n2);
  gemm_db<128,128,32, 1,1,0,1><<<512, blk, 0, stream>>>(n2, W1T, B1, nullptr, h1, 2048, 4096, 1024);
  gemm_db<64,64,64, 1,0,1,0><<<512, blk, 0, stream>>>(h1, W2T, B2, x1, out, 2048, 1024, 4096);
}

// Round 9
// 139.042 us; speedup vs baseline: 3.5636x; 1.1943x over previous
//
#include <hip/hip_runtime.h>
#include <hip/hip_bf16.h>
#include <stdint.h>

#define D_MODEL 1024
#define S_LEN 1024
#define BATCH 2
#define NHEADS 16
#define DK 64
#define DFF 4096

typedef __attribute__((ext_vector_type(8))) short short8;
typedef __attribute__((ext_vector_type(4))) float f32x4;

__device__ __forceinline__ unsigned short f2bf(float f) {
  union { float f; unsigned u; } v; v.f = f;
  unsigned r = v.u + 0x7FFFu + ((v.u >> 16) & 1u);
  return (unsigned short)(r >> 16);
}

__device__ __forceinline__ float bf2f(unsigned short s) {
  union { float f; unsigned u; } v; v.u = ((unsigned)s) << 16;
  return v.f;
}

__device__ __forceinline__ void gll16(const void* g, void* l) {
  __builtin_amdgcn_global_load_lds(
      (const __attribute__((address_space(1))) void*)g,
      (__attribute__((address_space(3))) void*)l, 16, 0, 0);
}

// ---------------- LayerNorm: f32 in -> bf16 out (ddof=1 std per reference) ----
__global__ __launch_bounds__(256)
void ln_kernel(const float* __restrict__ x,
               const float* __restrict__ alpha,
               const float* __restrict__ beta,
               unsigned short* __restrict__ out) {
  const int row = blockIdx.x;
  const int tid = threadIdx.x;
  const float4 v = ((const float4*)(x + (int64_t)row * D_MODEL))[tid];
  float s = v.x + v.y + v.z + v.w;
  float ss = v.x * v.x + v.y * v.y + v.z * v.z + v.w * v.w;
  #pragma unroll
  for (int m = 32; m; m >>= 1) {
    s += __shfl_down(s, m);
    ss += __shfl_down(ss, m);
  }
  __shared__ float red[10];
  const int wave = tid >> 6;
  if ((tid & 63) == 0) { red[wave] = s; red[4 + wave] = ss; }
  __syncthreads();
  if (tid == 0) {
    float S = red[0] + red[1] + red[2] + red[3];
    float SS = red[4] + red[5] + red[6] + red[7];
    float mean = S * (1.f / 1024.f);
    float var = (SS - 1024.f * mean * mean) * (1.f / 1023.f);
    float inv = 1.f / (sqrtf(fmaxf(var, 0.f)) + 1e-6f);
    red[8] = mean; red[9] = inv;
  }
  __syncthreads();
  const float mean = red[8], inv = red[9];
  const float4 a = ((const float4*)alpha)[tid];
  const float4 bb = ((const float4*)beta)[tid];
  union { unsigned short us[4]; uint2 u2; } pk;
  pk.us[0] = f2bf(a.x * (v.x - mean) * inv + bb.x);
  pk.us[1] = f2bf(a.y * (v.y - mean) * inv + bb.y);
  pk.us[2] = f2bf(a.z * (v.z - mean) * inv + bb.z);
  pk.us[3] = f2bf(a.w * (v.w - mean) * inv + bb.w);
  ((uint2*)(out + (int64_t)row * D_MODEL))[tid] = pk.u2;
}

// ---------------- All four weight transposes in ONE launch -------------------
__global__ __launch_bounds__(256)
void wtall_kernel(const float* __restrict__ Wq, const float* __restrict__ Wo,
                  const float* __restrict__ W1, const float* __restrict__ W2,
                  unsigned short* __restrict__ WqT, unsigned short* __restrict__ WoT,
                  unsigned short* __restrict__ W1T, unsigned short* __restrict__ W2T) {
  __shared__ unsigned short tile[32][33];
  int id = blockIdx.x;
  const float* W; unsigned short* Wt; int K, N, bx, by;
  if (id < 1024)      { W = Wq; Wt = WqT; K = 1024; N = 1024; bx = id & 31;  by = id >> 5; }
  else if (id < 2048) { id -= 1024; W = Wo; Wt = WoT; K = 1024; N = 1024; bx = id & 31;  by = id >> 5; }
  else if (id < 6144) { id -= 2048; W = W1; Wt = W1T; K = 1024; N = 4096; bx = id & 127; by = id >> 7; }
  else                { id -= 6144; W = W2; Wt = W2T; K = 4096; N = 1024; bx = id & 31;  by = id >> 5; }
  const int k0 = by * 32, n0 = bx * 32;
  const int tx = threadIdx.x & 31, ty = threadIdx.x >> 5;
  #pragma unroll
  for (int i = 0; i < 4; i++) {
    int r = ty + i * 8;
    tile[r][tx] = f2bf(W[(int64_t)(k0 + r) * N + n0 + tx]);
  }
  __syncthreads();
  #pragma unroll
  for (int i = 0; i < 4; i++) {
    int r = ty + i * 8;
    Wt[(int64_t)(n0 + r) * K + k0 + tx] = tile[tx][r];
  }
}

// ---------------- per-head transpose: qkv[b][s][h*64+d] -> qkvT[b][h][d][s] --
__global__ __launch_bounds__(256)
void qkvt_kernel(const unsigned short* __restrict__ qkv,
                 unsigned short* __restrict__ qkvT) {
  __shared__ unsigned short tile[32][33];
  const int s0 = blockIdx.x * 32, d0 = blockIdx.y * 32, bh = blockIdx.z;
  const int b = bh >> 4, h = bh & 15;
  const int tx = threadIdx.x & 31, ty = threadIdx.x >> 5;
  #pragma unroll
  for (int i = 0; i < 4; i++) {
    int r = ty + i * 8;
    tile[r][tx] = qkv[(int64_t)(b * S_LEN + s0 + r) * D_MODEL + h * DK + d0 + tx];
  }
  __syncthreads();
  #pragma unroll
  for (int i = 0; i < 4; i++) {
    int r = ty + i * 8;
    qkvT[(int64_t)(bh * DK + d0 + r) * S_LEN + s0 + tx] = tile[tx][r];
  }
}

// ---------------- mask pre-layout: int32 [B,S,S] -> bf16 fragment table -------
__global__ __launch_bounds__(256)
void mprep_kernel(const int* __restrict__ mask, unsigned short* __restrict__ Mf) {
  const int gid = blockIdx.x * 256 + threadIdx.x;   // 262144 total
  const int lo = gid & 15;
  const int ktb = (gid >> 4) & 31;
  const int q4 = (gid >> 9) & 255;
  const int b = gid >> 17;
  const int* mrow = mask + ((int64_t)b << 20) + (int64_t)q4 * 4096 + ktb * 32 + lo;
  union { unsigned short us[8]; short8 v; } o;
  #pragma unroll
  for (int r = 0; r < 4; r++) {
    o.us[r * 2]     = mrow[r * 1024]      ? 0x3F80 : 0;
    o.us[r * 2 + 1] = mrow[r * 1024 + 16] ? 0x3F80 : 0;
  }
  ((short8*)Mf)[gid] = o.v;
}

// ---------------- GEMM (round-6 structure): C = A * Bt^T (+bias,+relu,+res) --
// Single-buffered LDS staging via global_load_lds, T2 chunk swizzle.
// KSPLIT=2: grid doubled, block handles K/2; f32 partial to outp (split 0) or
// outp2 (split 1); BIAS/RELU/RES ignored in that mode.
template<int BM, int BN, int BK, int BIAS, int RELU, int RES, int OUTBF, int KSPLIT>
__global__ __launch_bounds__(256)
void gemm_t(const unsigned short* __restrict__ A,
            const unsigned short* __restrict__ Bt,
            const float* __restrict__ bias,
            const float* __restrict__ res,
            void* __restrict__ outp,
            void* __restrict__ outp2,
            int M, int N, int K) {
  constexpr int NCH = BK / 8;
  constexpr int RPW = 512 / BK;
  constexpr int RPR = 2048 / BK;
  constexpr int RA = (BM * BK) / 2048;
  constexpr int RB = (BN * BK) / 2048;
  constexpr int MI = BM / 32;
  constexpr int NJ = BN / 32;
  constexpr int KK = BK / 32;

  __shared__ __align__(16) unsigned short As[BM * BK];
  __shared__ __align__(16) unsigned short Bs[BN * BK];

  const int tid = threadIdx.x;
  const int lane = tid & 63;
  const int wave = tid >> 6;
  const int lo = lane & 15, hi = lane >> 4;

  int bid = blockIdx.x;
  int split = 0;
  if (KSPLIT == 2) { split = bid & 1; bid >>= 1; }
  const int cpx = (gridDim.x / KSPLIT) >> 3;
  const int sid = (bid & 7) * cpx + (bid >> 3);
  const int nbx = N / BN;
  const int n0 = (sid % nbx) * BN;
  const int m0 = (sid / nbx) * BM;
  const int wr = (wave >> 1) * (BM / 2);
  const int wc = (wave & 1) * (BN / 2);

  auto swz = [](int row, int c) -> int {
    if (BK == 128) return c ^ ((row & 7) << 1);
    if (BK == 64)  return c ^ (row & 7);
    return c ^ ((row >> 1) & 3);   // BK == 32
  };

  const int sr = lane / NCH;
  const int sc = lane % NCH;

  f32x4 acc[MI][NJ] = {};

  const int kbeg = split * (K / KSPLIT);
  const int kend = kbeg + K / KSPLIT;
  for (int k0 = kbeg; k0 < kend; k0 += BK) {
    #pragma unroll
    for (int r = 0; r < RA; r++) {
      const int row = r * RPR + wave * RPW + sr;
      gll16(A + (int64_t)(m0 + row) * K + k0 + swz(row, sc) * 8,
            &As[r * 2048 + wave * 512]);
    }
    #pragma unroll
    for (int r = 0; r < RB; r++) {
      const int row = r * RPR + wave * RPW + sr;
      gll16(Bt + (int64_t)(n0 + row) * K + k0 + swz(row, sc) * 8,
            &Bs[r * 2048 + wave * 512]);
    }
    __syncthreads();
    #pragma unroll
    for (int kk = 0; kk < KK; kk++) {
      short8 af[MI], bfr[NJ];
      #pragma unroll
      for (int t = 0; t < MI; t++) {
        const int row = wr + t * 16 + lo;
        af[t] = *(const short8*)&As[row * BK + swz(row, kk * 4 + hi) * 8];
      }
      #pragma unroll
      for (int t = 0; t < NJ; t++) {
        const int row = wc + t * 16 + lo;
        bfr[t] = *(const short8*)&Bs[row * BK + swz(row, kk * 4 + hi) * 8];
      }
      #pragma unroll
      for (int i = 0; i < MI; i++)
        #pragma unroll
        for (int j = 0; j < NJ; j++)
          acc[i][j] = __builtin_amdgcn_mfma_f32_16x16x32_bf16(af[i], bfr[j], acc[i][j], 0, 0, 0);
    }
    __syncthreads();
  }

  float* Pout = (KSPLIT == 2) ? (split ? (float*)outp2 : (float*)outp) : nullptr;
  #pragma unroll
  for (int i = 0; i < MI; i++) {
    const int row = m0 + wr + i * 16 + hi * 4;
    #pragma unroll
    for (int j = 0; j < NJ; j++) {
      const int col = n0 + wc + j * 16 + lo;
      #pragma unroll
      for (int r = 0; r < 4; r++) {
        float v = acc[i][j][r];
        if (KSPLIT == 2) {
          Pout[(int64_t)(row + r) * N + col] = v;
        } else {
          if (BIAS) v += bias[col];
          if (RELU) v = fmaxf(v, 0.f);
          if (RES)  v += res[(int64_t)(row + r) * N + col];
          if (OUTBF)
            ((unsigned short*)outp)[(int64_t)(row + r) * N + col] = f2bf(v);
          else
            ((float*)outp)[(int64_t)(row + r) * N + col] = v;
        }
      }
    }
  }
}

// ---------------- FFN2 combine: out = x1(out) + B2 + P0 + P1 -----------------
__global__ __launch_bounds__(256)
void fcomb_kernel(const float* __restrict__ P0, const float* __restrict__ P1,
                  const float* __restrict__ bias, float* __restrict__ out) {
  const int i4 = blockIdx.x * 256 + threadIdx.x;     // 524288 float4
  const float4 a = ((const float4*)P0)[i4];
  const float4 b = ((const float4*)P1)[i4];
  const float4 bb = ((const float4*)bias)[i4 & 255]; // N=1024 -> 256 float4/row
  float4 c = ((const float4*)out)[i4];
  c.x += a.x + b.x + bb.x;
  c.y += a.y + b.y + bb.y;
  c.z += a.z + b.z + bb.z;
  c.w += a.w + b.w + bb.w;
  ((float4*)out)[i4] = c;
}

// -------- fused attention: LDS-staged K/V/M tiles, KV-split x2, XCD-local ----
__global__ __launch_bounds__(256)
void attn_kernel(const unsigned short* __restrict__ qkv,
                 const unsigned short* __restrict__ qkvT,
                 const unsigned short* __restrict__ Mf,
                 float* __restrict__ part,
                 float* __restrict__ psum) {
  __shared__ __align__(16) unsigned short Ks[64 * 64];
  __shared__ __align__(16) unsigned short Vs[64 * 64];
  __shared__ __align__(16) unsigned short Ms[512 * 8];
  __shared__ __align__(16) unsigned short Plds[4][16 * 40];
  const int tid = threadIdx.x;
  const int lane = tid & 63;
  const int wave = tid >> 6;
  const int lo = lane & 15, hi = lane >> 4;
  const int L = blockIdx.x;            // 1024 blocks
  const int xcd = L & 7, idx = L >> 3;
  const int b = xcd >> 2;
  const int h = (xcd & 3) * 4 + (idx >> 5);
  const int split = (idx >> 4) & 1;
  const int qt = idx & 15;
  const int bh = b * 16 + h;
  const int q0 = qt * 64 + wave * 16;

  const unsigned short* qb =
      qkv + (int64_t)(b * S_LEN + q0 + lo) * D_MODEL + h * DK + hi * 8;
  const short8 qf0 = *(const short8*)qb;
  const short8 qf1 = *(const short8*)(qb + 32);

  f32x4 oacc[4] = {};
  float rsum[4] = {0.f, 0.f, 0.f, 0.f};
  unsigned short* Pw = Plds[wave];
  const int kbeg = split * 512;
  const int q4w = wave * 4 + hi;
  const int xr = lo & 7;

  for (int kti = 0; kti < 8; kti++) {
    const int kt = kbeg + kti * 64;
    #pragma unroll
    for (int r = 0; r < 2; r++) {
      const int c = r * 256 + tid;
      const int row = c >> 3;
      const int chg = (c & 7) ^ (row & 7);
      gll16(qkv + (int64_t)(b * S_LEN + kt + row) * D_MODEL + h * DK + chg * 8,
            &Ks[(r * 256 + wave * 64) * 8]);
      gll16(qkvT + (int64_t)(bh * DK + row) * S_LEN + kt + chg * 8,
            &Vs[(r * 256 + wave * 64) * 8]);
      const int q4l = c >> 5;
      const int u2 = (c >> 4) & 1;
      const int log = (c & 15) ^ q4l;
      gll16(Mf + ((int64_t)((b * 256 + qt * 16 + q4l) * 32 + (kt >> 5) + u2) * 16 + log) * 8,
            &Ms[(r * 256 + wave * 64) * 8]);
    }
    __syncthreads();
    #pragma unroll
    for (int u = 0; u < 2; u++) {
      const short8 kf00 = *(const short8*)&Ks[((u * 32 + lo) * 8 + (hi ^ xr)) * 8];
      const short8 kf01 = *(const short8*)&Ks[((u * 32 + lo) * 8 + ((4 + hi) ^ xr)) * 8];
      const short8 kf10 = *(const short8*)&Ks[((u * 32 + 16 + lo) * 8 + (hi ^ xr)) * 8];
      const short8 kf11 = *(const short8*)&Ks[((u * 32 + 16 + lo) * 8 + ((4 + hi) ^ xr)) * 8];
      const short8 mf = *(const short8*)&Ms[(q4w * 32 + u * 16 + (lo ^ q4w)) * 8];
      f32x4 s0 = {}, s1 = {};
      s0 = __builtin_amdgcn_mfma_f32_16x16x32_bf16(qf0, kf00, s0, 0, 0, 0);
      s0 = __builtin_amdgcn_mfma_f32_16x16x32_bf16(qf1, kf01, s0, 0, 0, 0);
      s1 = __builtin_amdgcn_mfma_f32_16x16x32_bf16(qf0, kf10, s1, 0, 0, 0);
      s1 = __builtin_amdgcn_mfma_f32_16x16x32_bf16(qf1, kf11, s1, 0, 0, 0);
      #pragma unroll
      for (int r = 0; r < 4; r++) {
        const float m0_ = bf2f((unsigned short)mf[r * 2]);
        const float m1_ = bf2f((unsigned short)mf[r * 2 + 1]);
        const float e0_ = __expf(s0[r] * 0.125f);
        const float e1_ = __expf(s1[r] * 0.125f);
        const float p0_ = fmaf(m0_, e0_ - 1.f, 1.f);
        const float p1_ = fmaf(m1_, e1_ - 1.f, 1.f);
        rsum[r] += p0_ + p1_;
        Pw[(hi * 4 + r) * 40 + lo]      = f2bf(p0_);
        Pw[(hi * 4 + r) * 40 + 16 + lo] = f2bf(p1_);
      }
      const short8 pf = *(const short8*)&Pw[lo * 40 + hi * 8];
      #pragma unroll
      for (int t = 0; t < 4; t++) {
        const short8 vf = *(const short8*)&Vs[((t * 16 + lo) * 8 + ((u * 4 + hi) ^ xr)) * 8];
        oacc[t] = __builtin_amdgcn_mfma_f32_16x16x32_bf16(pf, vf, oacc[t], 0, 0, 0);
      }
    }
    __syncthreads();
  }

  #pragma unroll
  for (int m = 1; m < 16; m <<= 1)
    #pragma unroll
    for (int r = 0; r < 4; r++) rsum[r] += __shfl_xor(rsum[r], m);

  const int64_t prow = (int64_t)(split * 32 + bh) * 1024;
  #pragma unroll
  for (int t = 0; t < 4; t++)
    #pragma unroll
    for (int r = 0; r < 4; r++)
      part[(prow + q0 + hi * 4 + r) * 64 + t * 16 + lo] = oacc[t][r];
  if (lo == 0)
    #pragma unroll
    for (int r = 0; r < 4; r++)
      psum[prow + q0 + hi * 4 + r] = rsum[r];
}

// ---------------- combine KV-split partials -> ctx (bf16) --------------------
__global__ __launch_bounds__(256)
void acomb_kernel(const float* __restrict__ part,
                  const float* __restrict__ psum,
                  unsigned short* __restrict__ ctx) {
  const int idx4 = blockIdx.x * 256 + threadIdx.x;   // 524288
  const int d4 = idx4 & 15;
  const int q = (idx4 >> 4) & 1023;
  const int bh = idx4 >> 14;
  const int b = bh >> 4, h = bh & 15;
  const float4* p4 = (const float4*)part;
  const float4 a0 = p4[(int64_t)(bh * 1024 + q) * 16 + d4];
  const float4 a1 = p4[524288 + (int64_t)(bh * 1024 + q) * 16 + d4];
  const float rs = psum[bh * 1024 + q] + psum[32768 + bh * 1024 + q];
  const float inv = 1.f / rs;
  union { unsigned short us[4]; uint2 u2; } pk;
  pk.us[0] = f2bf((a0.x + a1.x) * inv);
  pk.us[1] = f2bf((a0.y + a1.y) * inv);
  pk.us[2] = f2bf((a0.z + a1.z) * inv);
  pk.us[3] = f2bf((a0.w + a1.w) * inv);
  *(uint2*)(ctx + (int64_t)(b * S_LEN + q) * D_MODEL + h * DK + d4 * 4) = pk.u2;
}

// -----------------------------------------------------------------------------
extern "C" void kernel_launch(void* const* d_in, const int* in_sizes, int n_in,
                              void* d_out, int out_size, void* d_ws, size_t ws_size,
                              hipStream_t stream) {
  (void)in_sizes; (void)n_in; (void)out_size; (void)ws_size;
  const float* x    = (const float*)d_in[0];
  const int*   mask = (const int*)d_in[1];
  const float* Wq   = (const float*)d_in[2];
  const float* Wo   = (const float*)d_in[3];
  const float* W1   = (const float*)d_in[4];
  const float* B1   = (const float*)d_in[5];
  const float* W2   = (const float*)d_in[6];
  const float* B2   = (const float*)d_in[7];
  const float* ln1a = (const float*)d_in[8];
  const float* ln1b = (const float*)d_in[9];
  const float* ln2a = (const float*)d_in[10];
  const float* ln2b = (const float*)d_in[11];
  float* out = (float*)d_out;

  char* ws = (char*)d_ws;
  unsigned short* WqT  = (unsigned short*)(ws);                     // [0,2) MB
  unsigned short* WoT  = (unsigned short*)(ws + (2ull  << 20));     // [2,4)
  unsigned short* W1T  = (unsigned short*)(ws + (4ull  << 20));     // [4,12)
  float*          Pf0  = (float*)(ws + (4ull  << 20));              // FFN2 partial 0 (W1T dead)
  unsigned short* W2T  = (unsigned short*)(ws + (12ull << 20));     // [12,20)
  unsigned short* n1   = (unsigned short*)(ws + (20ull << 20));     // [20,24)
  float*          psum = (float*)(ws + (20ull << 20));              // reuses n1
  unsigned short* qkv  = (unsigned short*)(ws + (24ull << 20));     // [24,28)
  unsigned short* qkvT = (unsigned short*)(ws + (28ull << 20));     // [28,32)
  unsigned short* Mf   = (unsigned short*)(ws + (32ull << 20));     // [32,36)
  unsigned short* ctx  = (unsigned short*)(ws + (32ull << 20));     // [32,36)
  float*          Pf1  = (float*)(ws + (32ull << 20));              // FFN2 partial 1 (ctx+n2 dead)
  unsigned short* n2   = (unsigned short*)(ws + (36ull << 20));     // [36,40)
  float*          part = (float*)(ws + (40ull << 20));              // [40,56)
  unsigned short* h1   = (unsigned short*)(ws + (40ull << 20));     // [40,56)
  float* x1 = out;  // residual-1 result lives in d_out (fully rewritten later)

  dim3 blk(256);
  wtall_kernel<<<10240, blk, 0, stream>>>(Wq, Wo, W1, W2, WqT, WoT, W1T, W2T);
  mprep_kernel<<<1024, blk, 0, stream>>>(mask, Mf);

  ln_kernel<<<2048, blk, 0, stream>>>(x, ln1a, ln1b, n1);
  gemm_t<64,64,128, 0,0,0,1,1><<<512, blk, 0, stream>>>(n1, WqT, nullptr, nullptr, qkv, nullptr, 2048, 1024, 1024);
  qkvt_kernel<<<dim3(32, 2, 32), blk, 0, stream>>>(qkv, qkvT);
  attn_kernel<<<1024, blk, 0, stream>>>(qkv, qkvT, Mf, part, psum);
  acomb_kernel<<<2048, blk, 0, stream>>>(part, psum, ctx);
  gemm_t<64,64,128, 0,0,1,0,1><<<512, blk, 0, stream>>>(ctx, WoT, nullptr, x, x1, nullptr, 2048, 1024, 1024);
  ln_kernel<<<2048, blk, 0, stream>>>(x1, ln2a, ln2b, n2);
  gemm_t<128,128,64, 1,1,0,1,1><<<512, blk, 0, stream>>>(n2, W1T, B1, nullptr, h1, nullptr, 2048, 4096, 1024);
  // FFN2: K-split x2 -> f32 partials (Pf0 in dead W1T region, Pf1 in dead ctx/n2)
  gemm_t<64,64,128, 0,0,0,0,2><<<1024, blk, 0, stream>>>(h1, W2T, nullptr, nullptr, Pf0, Pf1, 2048, 1024, 4096);
  fcomb_kernel<<<2048, blk, 0, stream>>>(Pf0, Pf1, B2, out);
}